// Round 2
// baseline (423.965 us; speedup 1.0000x reference)
//
#include <hip/hip_runtime.h>
#include <math.h>

// ---------------------------------------------------------------------------
// GAT x2 + linear + log_softmax on MI355X. R13.
//   - CSR build restructured to kill atomic-return serialization (R12 post-
//     mortem: blocks parked waiting on returning bucketCount atomics):
//     * k1 fused_count_gemm: per-node degree via FIRE-AND-FORGET global
//       atomics (no wave ever waits) + LDS bucket hist -> non-returning
//       chunk-sum atomics. gemm1 co-resident, unchanged.
//     * k2 node_offs: offs = gbase + excl-scan(deg) per 512-node chunk;
//       also seeds cursor[] = offs[].
//     * k3 edge_scatter: pos = atomicAdd(&cursor[dst]) (chains ~16 deep over
//       100K addresses, fully parallel); csr[pos] = src.
//     * ebuf intermediate + bucket_csr second pass DELETED (saves 13MB of
//       scattered write+read traffic and the rank-capture machinery).
//   - gat_agg / gemm_mfma2 / final_lsm unchanged.
// ---------------------------------------------------------------------------

#define NEG_SLOPE 0.2f
#define NEG_BIG -3.0e38f

#define BSHIFT 9
#define BSIZE 512            // nodes per offs chunk
#define CEPB 8192            // edges per count block

typedef __bf16 bf16x8 __attribute__((ext_vector_type(8)));
typedef __bf16 bf16x4 __attribute__((ext_vector_type(4)));
typedef float f32x4 __attribute__((ext_vector_type(4)));

__device__ __forceinline__ float lrelu(float x) {
    return x >= 0.f ? x : NEG_SLOPE * x;
}

__device__ __forceinline__ int wave_incl_scan(int v, int lane) {
#pragma unroll
    for (int d = 1; d < 64; d <<= 1) {
        int t = __shfl_up(v, d, 64);
        if (lane >= d) v += t;
    }
    return v;
}

// ---------------- fused: degree-count || gemm1 (K=128, fp32 A hi/lo) -------

__global__ __launch_bounds__(256) void fused_count_gemm(
        const int* __restrict__ dst, int* __restrict__ deg,
        int* __restrict__ bucketCount, int E, int CB,
        const float* __restrict__ X, const float* __restrict__ W,
        const float* __restrict__ a_src, const float* __restrict__ a_dst,
        __bf16* __restrict__ Hout, float* __restrict__ as_, float* __restrict__ ad_,
        int N, int nTiles) {
    constexpr int K = 128;
    __shared__ __bf16 Whi[64][K + 8];
    __shared__ __bf16 Wlo[64][K + 8];
    __shared__ int hist[256];

    if (blockIdx.x < (unsigned)CB) {
        // ---- count path: fire-and-forget atomics, zero wave stalls ----
        const int t = threadIdx.x;
        hist[t] = 0;
        __syncthreads();
        const int e0 = blockIdx.x * CEPB;
        const int e1 = min(e0 + CEPB, E);
        for (int e = e0 + t; e < e1; e += 256) {
            int d = dst[e];
            atomicAdd(&deg[d], 1);                 // non-returning
            atomicAdd(&hist[d >> BSHIFT], 1);      // LDS
        }
        __syncthreads();
        if (hist[t] > 0) atomicAdd(&bucketCount[t], hist[t]);  // non-returning
        return;
    }

    // ---- gemm path ----
    const int gbid = blockIdx.x - CB;
    for (int idx = threadIdx.x; idx < K * 64; idx += 256) {
        int k = idx >> 6, n = idx & 63;
        float w = W[idx];
        __bf16 hi = (__bf16)w;
        Whi[n][k] = hi;
        Wlo[n][k] = (__bf16)(w - (float)hi);
    }
    __syncthreads();

    const int lane  = threadIdx.x & 63;
    const int wave  = threadIdx.x >> 6;
    const int row16 = lane & 15;
    const int quad  = lane >> 4;

    float asv[4], adv[4];
#pragma unroll
    for (int t = 0; t < 4; ++t) {
        asv[t] = a_src[t * 16 + row16];
        adv[t] = a_dst[t * 16 + row16];
    }

    for (int tile = gbid; tile < nTiles; tile += 1024) {
        const int nbase = tile * 64;
        int gn = nbase + wave * 16 + row16;
        if (gn >= N) gn = N - 1;
        const float* __restrict__ xp = X + (size_t)gn * K + quad * 8;

        float4 xv[K / 16];
#pragma unroll
        for (int c = 0; c < K / 32; ++c) {
            xv[2 * c]     = *(const float4*)(xp + c * 32);
            xv[2 * c + 1] = *(const float4*)(xp + c * 32 + 4);
        }

        f32x4 acc[4] = {{0.f, 0.f, 0.f, 0.f}, {0.f, 0.f, 0.f, 0.f},
                        {0.f, 0.f, 0.f, 0.f}, {0.f, 0.f, 0.f, 0.f}};
#pragma unroll
        for (int kc = 0; kc < K; kc += 32) {
            float xs[8];
            *(float4*)&xs[0] = xv[kc / 16];
            *(float4*)&xs[4] = xv[kc / 16 + 1];
            bf16x8 ahi, alo;
#pragma unroll
            for (int j = 0; j < 8; ++j) {
                __bf16 hi = (__bf16)xs[j];
                ahi[j] = hi;
                alo[j] = (__bf16)(xs[j] - (float)hi);
            }
#pragma unroll
            for (int t = 0; t < 4; ++t) {
                bf16x8 bhi = *(const bf16x8*)&Whi[t * 16 + row16][kc + quad * 8];
                bf16x8 blo = *(const bf16x8*)&Wlo[t * 16 + row16][kc + quad * 8];
                acc[t] = __builtin_amdgcn_mfma_f32_16x16x32_bf16(ahi, bhi, acc[t], 0, 0, 0);
                acc[t] = __builtin_amdgcn_mfma_f32_16x16x32_bf16(ahi, blo, acc[t], 0, 0, 0);
                acc[t] = __builtin_amdgcn_mfma_f32_16x16x32_bf16(alo, bhi, acc[t], 0, 0, 0);
            }
        }

        float ps[4] = {0.f, 0.f, 0.f, 0.f};
        float pd[4] = {0.f, 0.f, 0.f, 0.f};
#pragma unroll
        for (int t = 0; t < 4; ++t) {
#pragma unroll
            for (int r = 0; r < 4; ++r) {
                int gm = nbase + wave * 16 + quad * 4 + r;
                if (gm < N) Hout[(size_t)gm * 64 + t * 16 + row16] = (__bf16)acc[t][r];
                ps[r] = fmaf(acc[t][r], asv[t], ps[r]);
                pd[r] = fmaf(acc[t][r], adv[t], pd[r]);
            }
        }
#pragma unroll
        for (int r = 0; r < 4; ++r) {
#pragma unroll
            for (int d = 1; d < 16; d <<= 1) {
                ps[r] += __shfl_xor(ps[r], d, 64);
                pd[r] += __shfl_xor(pd[r], d, 64);
            }
        }
        if (row16 == 0) {
#pragma unroll
            for (int r = 0; r < 4; ++r) {
                int gm = nbase + wave * 16 + quad * 4 + r;
                if (gm < N) { as_[gm] = ps[r]; ad_[gm] = pd[r]; }
            }
        }
    }
}

// ---------------- offs = exclusive scan of deg, seed cursor ----------------

__global__ __launch_bounds__(512) void node_offs(const int* __restrict__ deg,
                                                 const int* __restrict__ bucketCount,
                                                 int* __restrict__ offs,
                                                 int* __restrict__ cursor,
                                                 int N, int E) {
    __shared__ int gsum[8], wsum[8];
    const int b = blockIdx.x;
    const int t = threadIdx.x;
    const int lane = t & 63;
    const int w = t >> 6;

    // gbase = sum of bucketCount[0..b-1]
    int v = (t < 256 && t < b) ? bucketCount[t] : 0;
#pragma unroll
    for (int d = 32; d; d >>= 1) v += __shfl_xor(v, d, 64);
    if (lane == 0) gsum[w] = v;
    __syncthreads();
    int gbase = 0;
#pragma unroll
    for (int i = 0; i < 8; ++i) gbase += gsum[i];

    const int n = b * BSIZE + t;
    const int dv = (n < N) ? deg[n] : 0;
    int incl = wave_incl_scan(dv, lane);
    if (lane == 63) wsum[w] = incl;
    __syncthreads();
    int prefix = 0;
#pragma unroll
    for (int i = 0; i < 8; ++i) prefix += (i < w) ? wsum[i] : 0;
    int excl = incl - dv + prefix;
    if (n < N) {
        int o = gbase + excl;
        offs[n] = o;
        cursor[n] = o;
    }
    if (b == 0 && t == 0) offs[N] = E;
}

// ---------------- edge scatter into CSR (parallel short atomic chains) -----

__global__ __launch_bounds__(256) void edge_scatter(const int* __restrict__ src,
                                                    const int* __restrict__ dst,
                                                    int* __restrict__ cursor,
                                                    int* __restrict__ csr, int E) {
    int e = blockIdx.x * 256 + threadIdx.x;
    if (e >= E) return;
    int s = src[e];
    int d = dst[e];
    int pos = atomicAdd(&cursor[d], 1);
    csr[pos] = s;
}

// ---------------- MFMA GEMM layer-2 (K=64, bf16 A, 2-term) ----------------

__global__ __launch_bounds__(256) void gemm_mfma2(const __bf16* __restrict__ X,
                                                  const float* __restrict__ W,
                                                  const float* __restrict__ a_src,
                                                  const float* __restrict__ a_dst,
                                                  __bf16* __restrict__ Hout,
                                                  float* __restrict__ as_,
                                                  float* __restrict__ ad_,
                                                  int N, int nTiles) {
    constexpr int K = 64;
    __shared__ __bf16 Whi[64][K + 8];
    __shared__ __bf16 Wlo[64][K + 8];
    for (int idx = threadIdx.x; idx < K * 64; idx += 256) {
        int k = idx >> 6, n = idx & 63;
        float w = W[idx];
        __bf16 hi = (__bf16)w;
        Whi[n][k] = hi;
        Wlo[n][k] = (__bf16)(w - (float)hi);
    }
    __syncthreads();

    const int lane  = threadIdx.x & 63;
    const int wave  = threadIdx.x >> 6;
    const int row16 = lane & 15;
    const int quad  = lane >> 4;

    float asv[4], adv[4];
#pragma unroll
    for (int t = 0; t < 4; ++t) {
        asv[t] = a_src[t * 16 + row16];
        adv[t] = a_dst[t * 16 + row16];
    }

    for (int tile = blockIdx.x; tile < nTiles; tile += gridDim.x) {
        const int nbase = tile * 64;
        int gn = nbase + wave * 16 + row16;
        if (gn >= N) gn = N - 1;
        const __bf16* __restrict__ xp = X + (size_t)gn * K + quad * 8;
        bf16x8 a0 = *(const bf16x8*)(xp);
        bf16x8 a1 = *(const bf16x8*)(xp + 32);

        f32x4 acc[4] = {{0.f, 0.f, 0.f, 0.f}, {0.f, 0.f, 0.f, 0.f},
                        {0.f, 0.f, 0.f, 0.f}, {0.f, 0.f, 0.f, 0.f}};
#pragma unroll
        for (int kc = 0; kc < K; kc += 32) {
            bf16x8 a = (kc == 0) ? a0 : a1;
#pragma unroll
            for (int t = 0; t < 4; ++t) {
                bf16x8 bhi = *(const bf16x8*)&Whi[t * 16 + row16][kc + quad * 8];
                bf16x8 blo = *(const bf16x8*)&Wlo[t * 16 + row16][kc + quad * 8];
                acc[t] = __builtin_amdgcn_mfma_f32_16x16x32_bf16(a, bhi, acc[t], 0, 0, 0);
                acc[t] = __builtin_amdgcn_mfma_f32_16x16x32_bf16(a, blo, acc[t], 0, 0, 0);
            }
        }

        float ps[4] = {0.f, 0.f, 0.f, 0.f};
        float pd[4] = {0.f, 0.f, 0.f, 0.f};
#pragma unroll
        for (int t = 0; t < 4; ++t) {
#pragma unroll
            for (int r = 0; r < 4; ++r) {
                int gm = nbase + wave * 16 + quad * 4 + r;
                if (gm < N) Hout[(size_t)gm * 64 + t * 16 + row16] = (__bf16)acc[t][r];
                ps[r] = fmaf(acc[t][r], asv[t], ps[r]);
                pd[r] = fmaf(acc[t][r], adv[t], pd[r]);
            }
        }
#pragma unroll
        for (int r = 0; r < 4; ++r) {
#pragma unroll
            for (int d = 1; d < 16; d <<= 1) {
                ps[r] += __shfl_xor(ps[r], d, 64);
                pd[r] += __shfl_xor(pd[r], d, 64);
            }
        }
        if (row16 == 0) {
#pragma unroll
            for (int r = 0; r < 4; ++r) {
                int gm = nbase + wave * 16 + quad * 4 + r;
                if (gm < N) { as_[gm] = ps[r]; ad_[gm] = pd[r]; }
            }
        }
    }
}

// ---------------- fused segment softmax + aggregation (4x16, bf16x4) -------

__global__ __launch_bounds__(256) void gat_agg(const __bf16* __restrict__ h,
                                               const float* __restrict__ as_,
                                               const float* __restrict__ ad_,
                                               const float* __restrict__ bias,
                                               const int* __restrict__ offs,
                                               const int* __restrict__ csr,
                                               __bf16* __restrict__ out,
                                               int N, int do_relu) {
    int gtid = blockIdx.x * blockDim.x + threadIdx.x;
    int n = __builtin_amdgcn_readfirstlane(gtid >> 6);
    if (n >= N) return;
    const int lane = threadIdx.x & 63;
    const int g  = lane >> 4;   // edge group 0..3
    const int fl = lane & 15;   // feature quad index

    int beg = offs[n], end = offs[n + 1];
    float adn = ad_[n];
    float p_self = __expf(lrelu(as_[n] + adn));

    float den = p_self;
    float ax, ay, az, aw;
    {
        bf16x4 t = *(const bf16x4*)(h + (size_t)n * 64 + fl * 4);
        float m0 = (g == 0) ? p_self : 0.f;
        ax = m0 * (float)t[0];
        ay = m0 * (float)t[1];
        az = m0 * (float)t[2];
        aw = m0 * (float)t[3];
    }

    for (int c0 = beg; c0 < end; c0 += 64) {
        int cnt = end - c0;
        if (cnt > 64) cnt = 64;
        int   s_l = (lane < cnt) ? csr[c0 + lane] : 0;
        float p_l = (lane < cnt) ? __expf(lrelu(as_[s_l] + adn)) : 0.f;
        float csum = p_l;
#pragma unroll
        for (int d = 32; d; d >>= 1) csum += __shfl_xor(csum, d, 64);
        den += csum;

        int rounds = (cnt + 3) >> 2;
        for (int r = 0; r < rounds; r += 4) {
            int j0 = (r + 0) * 4 + g, j1 = (r + 1) * 4 + g;
            int j2 = (r + 2) * 4 + g, j3 = (r + 3) * 4 + g;
            float w0 = __shfl(p_l, j0, 64), w1 = __shfl(p_l, j1, 64);
            float w2 = __shfl(p_l, j2, 64), w3 = __shfl(p_l, j3, 64);
            int s0 = __shfl(s_l, j0, 64), s1 = __shfl(s_l, j1, 64);
            int s2 = __shfl(s_l, j2, 64), s3 = __shfl(s_l, j3, 64);
            bf16x4 h0 = *(const bf16x4*)(h + (size_t)s0 * 64 + fl * 4);
            bf16x4 h1 = *(const bf16x4*)(h + (size_t)s1 * 64 + fl * 4);
            bf16x4 h2 = *(const bf16x4*)(h + (size_t)s2 * 64 + fl * 4);
            bf16x4 h3 = *(const bf16x4*)(h + (size_t)s3 * 64 + fl * 4);
            ax = fmaf(w0, (float)h0[0], ax); ay = fmaf(w0, (float)h0[1], ay);
            az = fmaf(w0, (float)h0[2], az); aw = fmaf(w0, (float)h0[3], aw);
            ax = fmaf(w1, (float)h1[0], ax); ay = fmaf(w1, (float)h1[1], ay);
            az = fmaf(w1, (float)h1[2], az); aw = fmaf(w1, (float)h1[3], aw);
            ax = fmaf(w2, (float)h2[0], ax); ay = fmaf(w2, (float)h2[1], ay);
            az = fmaf(w2, (float)h2[2], az); aw = fmaf(w2, (float)h2[3], aw);
            ax = fmaf(w3, (float)h3[0], ax); ay = fmaf(w3, (float)h3[1], ay);
            az = fmaf(w3, (float)h3[2], az); aw = fmaf(w3, (float)h3[3], aw);
        }
    }

#pragma unroll
    for (int d = 16; d <= 32; d <<= 1) {
        ax += __shfl_xor(ax, d, 64);
        ay += __shfl_xor(ay, d, 64);
        az += __shfl_xor(az, d, 64);
        aw += __shfl_xor(aw, d, 64);
    }
    if (g == 0) {
        float inv = 1.f / (den + 1e-16f);
        const float4 b4 = *(const float4*)(bias + fl * 4);
        bf16x4 ov;
        float o0 = fmaf(ax, inv, b4.x);
        float o1 = fmaf(ay, inv, b4.y);
        float o2 = fmaf(az, inv, b4.z);
        float o3 = fmaf(aw, inv, b4.w);
        if (do_relu) {
            o0 = fmaxf(o0, 0.f); o1 = fmaxf(o1, 0.f);
            o2 = fmaxf(o2, 0.f); o3 = fmaxf(o3, 0.f);
        }
        ov[0] = (__bf16)o0; ov[1] = (__bf16)o1;
        ov[2] = (__bf16)o2; ov[3] = (__bf16)o3;
        *(bf16x4*)(out + (size_t)n * 64 + fl * 4) = ov;
    }
}

// ---------------- final linear (bf16 A, 2-term) + log_softmax --------------

__global__ __launch_bounds__(256) void final_lsm(const __bf16* __restrict__ h,
                                                 const float* __restrict__ Wl,
                                                 const float* __restrict__ bl,
                                                 float* __restrict__ out,
                                                 int N, int nTiles) {
    __shared__ __bf16 Whi[48][72];
    __shared__ __bf16 Wlo[48][72];
    __shared__ float bls[48];
    for (int idx = threadIdx.x; idx < 48 * 64; idx += 256) {
        int c = idx >> 6, k = idx & 63;
        float w = (c < 40) ? Wl[k * 40 + c] : 0.f;
        __bf16 hi = (__bf16)w;
        Whi[c][k] = hi;
        Wlo[c][k] = (__bf16)(w - (float)hi);
    }
    if (threadIdx.x < 48) bls[threadIdx.x] = (threadIdx.x < 40) ? bl[threadIdx.x] : 0.f;
    __syncthreads();

    const int lane  = threadIdx.x & 63;
    const int wave  = threadIdx.x >> 6;
    const int col16 = lane & 15;
    const int quad  = lane >> 4;

    for (int tile = blockIdx.x; tile < nTiles; tile += gridDim.x) {
        const int nbase = tile * 64;
        int gn = nbase + wave * 16 + col16;
        if (gn >= N) gn = N - 1;
        const __bf16* __restrict__ xp = h + (size_t)gn * 64 + quad * 8;
        bf16x8 a0 = *(const bf16x8*)(xp);
        bf16x8 a1 = *(const bf16x8*)(xp + 32);

        f32x4 acc[3] = {{0.f, 0.f, 0.f, 0.f}, {0.f, 0.f, 0.f, 0.f},
                        {0.f, 0.f, 0.f, 0.f}};
#pragma unroll
        for (int kc = 0; kc < 64; kc += 32) {
            bf16x8 a = (kc == 0) ? a0 : a1;
#pragma unroll
            for (int t = 0; t < 3; ++t) {
                bf16x8 bhi = *(const bf16x8*)&Whi[t * 16 + col16][kc + quad * 8];
                bf16x8 blo = *(const bf16x8*)&Wlo[t * 16 + col16][kc + quad * 8];
                acc[t] = __builtin_amdgcn_mfma_f32_16x16x32_bf16(a, bhi, acc[t], 0, 0, 0);
                acc[t] = __builtin_amdgcn_mfma_f32_16x16x32_bf16(a, blo, acc[t], 0, 0, 0);
            }
        }

#pragma unroll
        for (int r = 0; r < 4; ++r) {
            int gm = nbase + wave * 16 + quad * 4 + r;
            float l0 = acc[0][r] + bls[col16];
            float l1 = acc[1][r] + bls[16 + col16];
            float l2 = (col16 < 8) ? (acc[2][r] + bls[32 + col16]) : NEG_BIG;
            float mx = fmaxf(fmaxf(l0, l1), l2);
#pragma unroll
            for (int d = 1; d < 16; d <<= 1) mx = fmaxf(mx, __shfl_xor(mx, d, 64));
            float s = __expf(l0 - mx) + __expf(l1 - mx) +
                      ((col16 < 8) ? __expf(l2 - mx) : 0.f);
#pragma unroll
            for (int d = 1; d < 16; d <<= 1) s += __shfl_xor(s, d, 64);
            float lse = mx + __logf(s);
            if (gm < N) {
                out[(size_t)gm * 40 + col16]      = l0 - lse;
                out[(size_t)gm * 40 + 16 + col16] = l1 - lse;
                if (col16 < 8) out[(size_t)gm * 40 + 32 + col16] = l2 - lse;
            }
        }
    }
}

// ---------------- launch ----------------

extern "C" void kernel_launch(void* const* d_in, const int* in_sizes, int n_in,
                              void* d_out, int out_size, void* d_ws, size_t ws_size,
                              hipStream_t stream) {
    const float* x      = (const float*)d_in[0];
    const int*   ei     = (const int*)d_in[1];
    const float* W1     = (const float*)d_in[2];
    const float* a_src1 = (const float*)d_in[3];
    const float* a_dst1 = (const float*)d_in[4];
    const float* b1     = (const float*)d_in[5];
    const float* W2     = (const float*)d_in[6];
    const float* a_src2 = (const float*)d_in[7];
    const float* a_dst2 = (const float*)d_in[8];
    const float* b2     = (const float*)d_in[9];
    const float* Wl     = (const float*)d_in[10];
    const float* bl     = (const float*)d_in[11];

    const int N = in_sizes[0] / 128;
    const int E = in_sizes[1] / 2;
    const int* src = ei;
    const int* dst = ei + E;
    const int nbuck = (N + BSIZE - 1) >> BSHIFT;
    const int CB = (E + CEPB - 1) / CEPB;

    char* p = (char*)d_ws;
    auto alloc = [&](size_t bytes) -> void* {
        void* r = (void*)p;
        p += (bytes + 255) & ~(size_t)255;
        return r;
    };
    int*      offs        = (int*)alloc((size_t)(N + 1) * 4);
    int*      deg         = (int*)alloc((size_t)N * 4);
    int*      bucketCount = (int*)alloc(256 * 4);
    int*      cursor      = (int*)alloc((size_t)N * 4);
    int*      csr         = (int*)alloc((size_t)E * 4);
    __bf16*   hbf         = (__bf16*)alloc((size_t)N * 64 * 2);  // gemm h out
    __bf16*   habg        = (__bf16*)alloc((size_t)N * 64 * 2);  // agg out
    float*    as_         = (float*)alloc((size_t)N * 4);
    float*    ad_         = (float*)alloc((size_t)N * 4);

    // deg and bucketCount are adjacent in the arena -> one memset covers both
    size_t degPad = ((size_t)N * 4 + 255) & ~(size_t)255;
    hipMemsetAsync(deg, 0, degPad + 256 * 4, stream);

    const int nTiles = (N + 63) / 64;
    int aggBlocks = (N * 64 + 255) / 256;

    fused_count_gemm<<<CB + 1024, 256, 0, stream>>>(
        dst, deg, bucketCount, E, CB,
        x, W1, a_src1, a_dst1, hbf, as_, ad_, N, nTiles);
    node_offs<<<nbuck, 512, 0, stream>>>(deg, bucketCount, offs, cursor, N, E);
    edge_scatter<<<(E + 255) / 256, 256, 0, stream>>>(src, dst, cursor, csr, E);
    gat_agg<<<aggBlocks, 256, 0, stream>>>(hbf, as_, ad_, b1, offs, csr, habg, N, 1);
    gemm_mfma2<<<1024, 256, 0, stream>>>(habg, W2, a_src2, a_dst2, hbf, as_, ad_, N, nTiles);
    gat_agg<<<aggBlocks, 256, 0, stream>>>(hbf, as_, ad_, b2, offs, csr, habg, N, 0);
    final_lsm<<<nTiles, 256, 0, stream>>>(habg, Wl, bl, (float*)d_out, N, nTiles);
}

// Round 3
// 338.232 us; speedup vs baseline: 1.2535x; 1.2535x over previous
//
#include <hip/hip_runtime.h>
#include <math.h>

// ---------------------------------------------------------------------------
// GAT x2 + linear + log_softmax on MI355X. R14.
//   - R13 post-mortem: random per-edge csr writes cost 106MB of 64B-line
//     write amplification (143us). Bucketing is REQUIRED for write locality.
//   - R12 post-mortem: R11's returning bucketCount atomics serialize blocks.
//   - R14 = bucketed CSR build with NO returning global atomics (radix-style):
//     k1 fused_hist_gemm: per-chunk LDS hist -> plain stores to
//        blockHist[bucket][chunk] + fire-and-forget deg/bucketCount atomics.
//        gemm1 co-resident; no block ever waits.
//     k2 offs_scan: role A: offs = gbase + scan(deg) per 512-node chunk;
//        role B: chunkBase[bucket][chunk] = excl-scan of blockHist over chunks.
//     k3 edge_place: LDS ranks + ebuf write at precomputed chunkBase.
//     k4 bucket_fill: per-bucket block, LDS per-node ranks,
//        csr[offs[node]+rank]=src (contiguous ~48KB write region per block).
//   - gat_agg / gemm_mfma2 / final_lsm unchanged from R11.
// ---------------------------------------------------------------------------

#define NEG_SLOPE 0.2f
#define NEG_BIG -3.0e38f

#define BSHIFT 9
#define BSIZE 512            // nodes per bucket
#define BCAP 12288           // edge capacity per bucket
#define CEPB 8192            // edges per hist/place chunk
#define CBPAD 256            // blockHist/chunkBase row stride (chunks)

typedef __bf16 bf16x8 __attribute__((ext_vector_type(8)));
typedef __bf16 bf16x4 __attribute__((ext_vector_type(4)));
typedef float f32x4 __attribute__((ext_vector_type(4)));

__device__ __forceinline__ float lrelu(float x) {
    return x >= 0.f ? x : NEG_SLOPE * x;
}

__device__ __forceinline__ int wave_incl_scan(int v, int lane) {
#pragma unroll
    for (int d = 1; d < 64; d <<= 1) {
        int t = __shfl_up(v, d, 64);
        if (lane >= d) v += t;
    }
    return v;
}

// ---------------- fused: chunk-hist || gemm1 (K=128, fp32 A hi/lo) ---------

__global__ __launch_bounds__(256) void fused_hist_gemm(
        const int* __restrict__ dst, int* __restrict__ deg,
        int* __restrict__ bucketCount, int* __restrict__ blockHist, int E, int CB,
        const float* __restrict__ X, const float* __restrict__ W,
        const float* __restrict__ a_src, const float* __restrict__ a_dst,
        __bf16* __restrict__ Hout, float* __restrict__ as_, float* __restrict__ ad_,
        int N, int nTiles) {
    constexpr int K = 128;
    __shared__ __bf16 Whi[64][K + 8];
    __shared__ __bf16 Wlo[64][K + 8];
    __shared__ int hist[256];

    if (blockIdx.x < (unsigned)CB) {
        // ---- hist path: fire-and-forget only, zero wave stalls ----
        const int t = threadIdx.x;
        hist[t] = 0;
        __syncthreads();
        const int c = blockIdx.x;
        const int e0 = c * CEPB;
        const int e1 = min(e0 + CEPB, E);
        for (int e = e0 + t; e < e1; e += 256) {
            int d = dst[e];
            atomicAdd(&deg[d], 1);                 // non-returning global
            atomicAdd(&hist[d >> BSHIFT], 1);      // LDS
        }
        __syncthreads();
        int hv = hist[t];
        blockHist[t * CBPAD + c] = hv;             // plain store
        if (hv > 0) atomicAdd(&bucketCount[t], hv);  // non-returning global
        return;
    }

    // ---- gemm path ----
    const int gbid = blockIdx.x - CB;
    for (int idx = threadIdx.x; idx < K * 64; idx += 256) {
        int k = idx >> 6, n = idx & 63;
        float w = W[idx];
        __bf16 hi = (__bf16)w;
        Whi[n][k] = hi;
        Wlo[n][k] = (__bf16)(w - (float)hi);
    }
    __syncthreads();

    const int lane  = threadIdx.x & 63;
    const int wave  = threadIdx.x >> 6;
    const int row16 = lane & 15;
    const int quad  = lane >> 4;

    float asv[4], adv[4];
#pragma unroll
    for (int t = 0; t < 4; ++t) {
        asv[t] = a_src[t * 16 + row16];
        adv[t] = a_dst[t * 16 + row16];
    }

    for (int tile = gbid; tile < nTiles; tile += 1024) {
        const int nbase = tile * 64;
        int gn = nbase + wave * 16 + row16;
        if (gn >= N) gn = N - 1;
        const float* __restrict__ xp = X + (size_t)gn * K + quad * 8;

        float4 xv[K / 16];
#pragma unroll
        for (int c = 0; c < K / 32; ++c) {
            xv[2 * c]     = *(const float4*)(xp + c * 32);
            xv[2 * c + 1] = *(const float4*)(xp + c * 32 + 4);
        }

        f32x4 acc[4] = {{0.f, 0.f, 0.f, 0.f}, {0.f, 0.f, 0.f, 0.f},
                        {0.f, 0.f, 0.f, 0.f}, {0.f, 0.f, 0.f, 0.f}};
#pragma unroll
        for (int kc = 0; kc < K; kc += 32) {
            float xs[8];
            *(float4*)&xs[0] = xv[kc / 16];
            *(float4*)&xs[4] = xv[kc / 16 + 1];
            bf16x8 ahi, alo;
#pragma unroll
            for (int j = 0; j < 8; ++j) {
                __bf16 hi = (__bf16)xs[j];
                ahi[j] = hi;
                alo[j] = (__bf16)(xs[j] - (float)hi);
            }
#pragma unroll
            for (int t = 0; t < 4; ++t) {
                bf16x8 bhi = *(const bf16x8*)&Whi[t * 16 + row16][kc + quad * 8];
                bf16x8 blo = *(const bf16x8*)&Wlo[t * 16 + row16][kc + quad * 8];
                acc[t] = __builtin_amdgcn_mfma_f32_16x16x32_bf16(ahi, bhi, acc[t], 0, 0, 0);
                acc[t] = __builtin_amdgcn_mfma_f32_16x16x32_bf16(ahi, blo, acc[t], 0, 0, 0);
                acc[t] = __builtin_amdgcn_mfma_f32_16x16x32_bf16(alo, bhi, acc[t], 0, 0, 0);
            }
        }

        float ps[4] = {0.f, 0.f, 0.f, 0.f};
        float pd[4] = {0.f, 0.f, 0.f, 0.f};
#pragma unroll
        for (int t = 0; t < 4; ++t) {
#pragma unroll
            for (int r = 0; r < 4; ++r) {
                int gm = nbase + wave * 16 + quad * 4 + r;
                if (gm < N) Hout[(size_t)gm * 64 + t * 16 + row16] = (__bf16)acc[t][r];
                ps[r] = fmaf(acc[t][r], asv[t], ps[r]);
                pd[r] = fmaf(acc[t][r], adv[t], pd[r]);
            }
        }
#pragma unroll
        for (int r = 0; r < 4; ++r) {
#pragma unroll
            for (int d = 1; d < 16; d <<= 1) {
                ps[r] += __shfl_xor(ps[r], d, 64);
                pd[r] += __shfl_xor(pd[r], d, 64);
            }
        }
        if (row16 == 0) {
#pragma unroll
            for (int r = 0; r < 4; ++r) {
                int gm = nbase + wave * 16 + quad * 4 + r;
                if (gm < N) { as_[gm] = ps[r]; ad_[gm] = pd[r]; }
            }
        }
    }
}

// ---------------- offs = scan(deg); chunkBase = scan(blockHist) ------------

__global__ __launch_bounds__(512) void offs_scan(const int* __restrict__ deg,
                                                 const int* __restrict__ bucketCount,
                                                 const int* __restrict__ blockHist,
                                                 int* __restrict__ offs,
                                                 int* __restrict__ chunkBase,
                                                 int N, int E, int nbuck, int CB) {
    __shared__ int gsum[8], wsum[8];
    const int t = threadIdx.x;
    const int lane = t & 63;
    const int w = t >> 6;

    if ((int)blockIdx.x < nbuck) {
        // role A: node offsets for 512-node chunk b
        const int b = blockIdx.x;
        int v = (t < 256 && t < b) ? bucketCount[t] : 0;
#pragma unroll
        for (int d = 32; d; d >>= 1) v += __shfl_xor(v, d, 64);
        if (lane == 0) gsum[w] = v;
        __syncthreads();
        int gbase = 0;
#pragma unroll
        for (int i = 0; i < 8; ++i) gbase += gsum[i];

        const int n = b * BSIZE + t;
        const int dv = (n < N) ? deg[n] : 0;
        int incl = wave_incl_scan(dv, lane);
        if (lane == 63) wsum[w] = incl;
        __syncthreads();
        int prefix = 0;
#pragma unroll
        for (int i = 0; i < 8; ++i) prefix += (i < w) ? wsum[i] : 0;
        if (n < N) offs[n] = gbase + incl - dv + prefix;
        if (b == 0 && t == 0) offs[N] = E;
    } else {
        // role B: chunk bases within bucket b
        const int b = blockIdx.x - nbuck;
        const int hv = (t < CB) ? blockHist[b * CBPAD + t] : 0;
        int incl = wave_incl_scan(hv, lane);
        if (lane == 63) wsum[w] = incl;
        __syncthreads();
        int prefix = 0;
#pragma unroll
        for (int i = 0; i < 8; ++i) prefix += (i < w) ? wsum[i] : 0;
        if (t < CB) chunkBase[b * CBPAD + t] = incl - hv + prefix;
    }
}

// ---------------- place edges into per-bucket ebuf (precomputed bases) -----

__global__ __launch_bounds__(256) void edge_place(const int* __restrict__ src,
                                                  const int* __restrict__ dst,
                                                  const int* __restrict__ chunkBase,
                                                  unsigned* __restrict__ ebuf, int E) {
    __shared__ int hist[256];
    __shared__ int base_s[256];
    const int t = threadIdx.x;
    hist[t] = 0;
    __syncthreads();
    const int c = blockIdx.x;
    const int e0 = c * CEPB;
    const int e1 = min(e0 + CEPB, E);
    int rr[CEPB / 256];
#pragma unroll
    for (int i = 0; i < CEPB / 256; ++i) {
        int e = e0 + i * 256 + t;
        if (e < e1) rr[i] = atomicAdd(&hist[dst[e] >> BSHIFT], 1);
    }
    __syncthreads();
    base_s[t] = chunkBase[t * CBPAD + c];
    __syncthreads();
#pragma unroll
    for (int i = 0; i < CEPB / 256; ++i) {
        int e = e0 + i * 256 + t;
        if (e < e1) {
            int d = dst[e];
            int b = d >> BSHIFT;
            ebuf[(size_t)b * BCAP + base_s[b] + rr[i]] =
                ((unsigned)src[e] << BSHIFT) | (unsigned)(d & (BSIZE - 1));
        }
    }
}

// ---------------- per-bucket CSR fill (LDS ranks, contiguous writes) -------

__global__ __launch_bounds__(1024) void bucket_fill(const unsigned* __restrict__ ebuf,
                                                    const int* __restrict__ offs,
                                                    int* __restrict__ csr, int N) {
    __shared__ int hist[512];
    __shared__ int obase[512];
    const int b = blockIdx.x;
    const int t = threadIdx.x;
    const int node0 = b * BSIZE;
    const int nloc = min(BSIZE, N - node0);
    if (t < 512) {
        hist[t] = 0;
        obase[t] = (t < nloc) ? offs[node0 + t] : 0;
    }
    __syncthreads();
    const int cnt = offs[node0 + nloc] - offs[node0];
    const unsigned* __restrict__ eb = ebuf + (size_t)b * BCAP;
    for (int idx = t; idx < cnt; idx += 1024) {
        unsigned rec = eb[idx];
        int local = rec & (BSIZE - 1);
        int rank = atomicAdd(&hist[local], 1);
        csr[obase[local] + rank] = (int)(rec >> BSHIFT);
    }
}

// ---------------- MFMA GEMM layer-2 (K=64, bf16 A, 2-term) ----------------

__global__ __launch_bounds__(256) void gemm_mfma2(const __bf16* __restrict__ X,
                                                  const float* __restrict__ W,
                                                  const float* __restrict__ a_src,
                                                  const float* __restrict__ a_dst,
                                                  __bf16* __restrict__ Hout,
                                                  float* __restrict__ as_,
                                                  float* __restrict__ ad_,
                                                  int N, int nTiles) {
    constexpr int K = 64;
    __shared__ __bf16 Whi[64][K + 8];
    __shared__ __bf16 Wlo[64][K + 8];
    for (int idx = threadIdx.x; idx < K * 64; idx += 256) {
        int k = idx >> 6, n = idx & 63;
        float w = W[idx];
        __bf16 hi = (__bf16)w;
        Whi[n][k] = hi;
        Wlo[n][k] = (__bf16)(w - (float)hi);
    }
    __syncthreads();

    const int lane  = threadIdx.x & 63;
    const int wave  = threadIdx.x >> 6;
    const int row16 = lane & 15;
    const int quad  = lane >> 4;

    float asv[4], adv[4];
#pragma unroll
    for (int t = 0; t < 4; ++t) {
        asv[t] = a_src[t * 16 + row16];
        adv[t] = a_dst[t * 16 + row16];
    }

    for (int tile = blockIdx.x; tile < nTiles; tile += gridDim.x) {
        const int nbase = tile * 64;
        int gn = nbase + wave * 16 + row16;
        if (gn >= N) gn = N - 1;
        const __bf16* __restrict__ xp = X + (size_t)gn * K + quad * 8;
        bf16x8 a0 = *(const bf16x8*)(xp);
        bf16x8 a1 = *(const bf16x8*)(xp + 32);

        f32x4 acc[4] = {{0.f, 0.f, 0.f, 0.f}, {0.f, 0.f, 0.f, 0.f},
                        {0.f, 0.f, 0.f, 0.f}, {0.f, 0.f, 0.f, 0.f}};
#pragma unroll
        for (int kc = 0; kc < K; kc += 32) {
            bf16x8 a = (kc == 0) ? a0 : a1;
#pragma unroll
            for (int t = 0; t < 4; ++t) {
                bf16x8 bhi = *(const bf16x8*)&Whi[t * 16 + row16][kc + quad * 8];
                bf16x8 blo = *(const bf16x8*)&Wlo[t * 16 + row16][kc + quad * 8];
                acc[t] = __builtin_amdgcn_mfma_f32_16x16x32_bf16(a, bhi, acc[t], 0, 0, 0);
                acc[t] = __builtin_amdgcn_mfma_f32_16x16x32_bf16(a, blo, acc[t], 0, 0, 0);
            }
        }

        float ps[4] = {0.f, 0.f, 0.f, 0.f};
        float pd[4] = {0.f, 0.f, 0.f, 0.f};
#pragma unroll
        for (int t = 0; t < 4; ++t) {
#pragma unroll
            for (int r = 0; r < 4; ++r) {
                int gm = nbase + wave * 16 + quad * 4 + r;
                if (gm < N) Hout[(size_t)gm * 64 + t * 16 + row16] = (__bf16)acc[t][r];
                ps[r] = fmaf(acc[t][r], asv[t], ps[r]);
                pd[r] = fmaf(acc[t][r], adv[t], pd[r]);
            }
        }
#pragma unroll
        for (int r = 0; r < 4; ++r) {
#pragma unroll
            for (int d = 1; d < 16; d <<= 1) {
                ps[r] += __shfl_xor(ps[r], d, 64);
                pd[r] += __shfl_xor(pd[r], d, 64);
            }
        }
        if (row16 == 0) {
#pragma unroll
            for (int r = 0; r < 4; ++r) {
                int gm = nbase + wave * 16 + quad * 4 + r;
                if (gm < N) { as_[gm] = ps[r]; ad_[gm] = pd[r]; }
            }
        }
    }
}

// ---------------- fused segment softmax + aggregation (4x16, bf16x4) -------

__global__ __launch_bounds__(256) void gat_agg(const __bf16* __restrict__ h,
                                               const float* __restrict__ as_,
                                               const float* __restrict__ ad_,
                                               const float* __restrict__ bias,
                                               const int* __restrict__ offs,
                                               const int* __restrict__ csr,
                                               __bf16* __restrict__ out,
                                               int N, int do_relu) {
    int gtid = blockIdx.x * blockDim.x + threadIdx.x;
    int n = __builtin_amdgcn_readfirstlane(gtid >> 6);
    if (n >= N) return;
    const int lane = threadIdx.x & 63;
    const int g  = lane >> 4;   // edge group 0..3
    const int fl = lane & 15;   // feature quad index

    int beg = offs[n], end = offs[n + 1];
    float adn = ad_[n];
    float p_self = __expf(lrelu(as_[n] + adn));

    float den = p_self;
    float ax, ay, az, aw;
    {
        bf16x4 t = *(const bf16x4*)(h + (size_t)n * 64 + fl * 4);
        float m0 = (g == 0) ? p_self : 0.f;
        ax = m0 * (float)t[0];
        ay = m0 * (float)t[1];
        az = m0 * (float)t[2];
        aw = m0 * (float)t[3];
    }

    for (int c0 = beg; c0 < end; c0 += 64) {
        int cnt = end - c0;
        if (cnt > 64) cnt = 64;
        int   s_l = (lane < cnt) ? csr[c0 + lane] : 0;
        float p_l = (lane < cnt) ? __expf(lrelu(as_[s_l] + adn)) : 0.f;
        float csum = p_l;
#pragma unroll
        for (int d = 32; d; d >>= 1) csum += __shfl_xor(csum, d, 64);
        den += csum;

        int rounds = (cnt + 3) >> 2;
        for (int r = 0; r < rounds; r += 4) {
            int j0 = (r + 0) * 4 + g, j1 = (r + 1) * 4 + g;
            int j2 = (r + 2) * 4 + g, j3 = (r + 3) * 4 + g;
            float w0 = __shfl(p_l, j0, 64), w1 = __shfl(p_l, j1, 64);
            float w2 = __shfl(p_l, j2, 64), w3 = __shfl(p_l, j3, 64);
            int s0 = __shfl(s_l, j0, 64), s1 = __shfl(s_l, j1, 64);
            int s2 = __shfl(s_l, j2, 64), s3 = __shfl(s_l, j3, 64);
            bf16x4 h0 = *(const bf16x4*)(h + (size_t)s0 * 64 + fl * 4);
            bf16x4 h1 = *(const bf16x4*)(h + (size_t)s1 * 64 + fl * 4);
            bf16x4 h2 = *(const bf16x4*)(h + (size_t)s2 * 64 + fl * 4);
            bf16x4 h3 = *(const bf16x4*)(h + (size_t)s3 * 64 + fl * 4);
            ax = fmaf(w0, (float)h0[0], ax); ay = fmaf(w0, (float)h0[1], ay);
            az = fmaf(w0, (float)h0[2], az); aw = fmaf(w0, (float)h0[3], aw);
            ax = fmaf(w1, (float)h1[0], ax); ay = fmaf(w1, (float)h1[1], ay);
            az = fmaf(w1, (float)h1[2], az); aw = fmaf(w1, (float)h1[3], aw);
            ax = fmaf(w2, (float)h2[0], ax); ay = fmaf(w2, (float)h2[1], ay);
            az = fmaf(w2, (float)h2[2], az); aw = fmaf(w2, (float)h2[3], aw);
            ax = fmaf(w3, (float)h3[0], ax); ay = fmaf(w3, (float)h3[1], ay);
            az = fmaf(w3, (float)h3[2], az); aw = fmaf(w3, (float)h3[3], aw);
        }
    }

#pragma unroll
    for (int d = 16; d <= 32; d <<= 1) {
        ax += __shfl_xor(ax, d, 64);
        ay += __shfl_xor(ay, d, 64);
        az += __shfl_xor(az, d, 64);
        aw += __shfl_xor(aw, d, 64);
    }
    if (g == 0) {
        float inv = 1.f / (den + 1e-16f);
        const float4 b4 = *(const float4*)(bias + fl * 4);
        bf16x4 ov;
        float o0 = fmaf(ax, inv, b4.x);
        float o1 = fmaf(ay, inv, b4.y);
        float o2 = fmaf(az, inv, b4.z);
        float o3 = fmaf(aw, inv, b4.w);
        if (do_relu) {
            o0 = fmaxf(o0, 0.f); o1 = fmaxf(o1, 0.f);
            o2 = fmaxf(o2, 0.f); o3 = fmaxf(o3, 0.f);
        }
        ov[0] = (__bf16)o0; ov[1] = (__bf16)o1;
        ov[2] = (__bf16)o2; ov[3] = (__bf16)o3;
        *(bf16x4*)(out + (size_t)n * 64 + fl * 4) = ov;
    }
}

// ---------------- final linear (bf16 A, 2-term) + log_softmax --------------

__global__ __launch_bounds__(256) void final_lsm(const __bf16* __restrict__ h,
                                                 const float* __restrict__ Wl,
                                                 const float* __restrict__ bl,
                                                 float* __restrict__ out,
                                                 int N, int nTiles) {
    __shared__ __bf16 Whi[48][72];
    __shared__ __bf16 Wlo[48][72];
    __shared__ float bls[48];
    for (int idx = threadIdx.x; idx < 48 * 64; idx += 256) {
        int c = idx >> 6, k = idx & 63;
        float w = (c < 40) ? Wl[k * 40 + c] : 0.f;
        __bf16 hi = (__bf16)w;
        Whi[c][k] = hi;
        Wlo[c][k] = (__bf16)(w - (float)hi);
    }
    if (threadIdx.x < 48) bls[threadIdx.x] = (threadIdx.x < 40) ? bl[threadIdx.x] : 0.f;
    __syncthreads();

    const int lane  = threadIdx.x & 63;
    const int wave  = threadIdx.x >> 6;
    const int col16 = lane & 15;
    const int quad  = lane >> 4;

    for (int tile = blockIdx.x; tile < nTiles; tile += gridDim.x) {
        const int nbase = tile * 64;
        int gn = nbase + wave * 16 + col16;
        if (gn >= N) gn = N - 1;
        const __bf16* __restrict__ xp = h + (size_t)gn * 64 + quad * 8;
        bf16x8 a0 = *(const bf16x8*)(xp);
        bf16x8 a1 = *(const bf16x8*)(xp + 32);

        f32x4 acc[3] = {{0.f, 0.f, 0.f, 0.f}, {0.f, 0.f, 0.f, 0.f},
                        {0.f, 0.f, 0.f, 0.f}};
#pragma unroll
        for (int kc = 0; kc < 64; kc += 32) {
            bf16x8 a = (kc == 0) ? a0 : a1;
#pragma unroll
            for (int t = 0; t < 3; ++t) {
                bf16x8 bhi = *(const bf16x8*)&Whi[t * 16 + col16][kc + quad * 8];
                bf16x8 blo = *(const bf16x8*)&Wlo[t * 16 + col16][kc + quad * 8];
                acc[t] = __builtin_amdgcn_mfma_f32_16x16x32_bf16(a, bhi, acc[t], 0, 0, 0);
                acc[t] = __builtin_amdgcn_mfma_f32_16x16x32_bf16(a, blo, acc[t], 0, 0, 0);
            }
        }

#pragma unroll
        for (int r = 0; r < 4; ++r) {
            int gm = nbase + wave * 16 + quad * 4 + r;
            float l0 = acc[0][r] + bls[col16];
            float l1 = acc[1][r] + bls[16 + col16];
            float l2 = (col16 < 8) ? (acc[2][r] + bls[32 + col16]) : NEG_BIG;
            float mx = fmaxf(fmaxf(l0, l1), l2);
#pragma unroll
            for (int d = 1; d < 16; d <<= 1) mx = fmaxf(mx, __shfl_xor(mx, d, 64));
            float s = __expf(l0 - mx) + __expf(l1 - mx) +
                      ((col16 < 8) ? __expf(l2 - mx) : 0.f);
#pragma unroll
            for (int d = 1; d < 16; d <<= 1) s += __shfl_xor(s, d, 64);
            float lse = mx + __logf(s);
            if (gm < N) {
                out[(size_t)gm * 40 + col16]      = l0 - lse;
                out[(size_t)gm * 40 + 16 + col16] = l1 - lse;
                if (col16 < 8) out[(size_t)gm * 40 + 32 + col16] = l2 - lse;
            }
        }
    }
}

// ---------------- launch ----------------

extern "C" void kernel_launch(void* const* d_in, const int* in_sizes, int n_in,
                              void* d_out, int out_size, void* d_ws, size_t ws_size,
                              hipStream_t stream) {
    const float* x      = (const float*)d_in[0];
    const int*   ei     = (const int*)d_in[1];
    const float* W1     = (const float*)d_in[2];
    const float* a_src1 = (const float*)d_in[3];
    const float* a_dst1 = (const float*)d_in[4];
    const float* b1     = (const float*)d_in[5];
    const float* W2     = (const float*)d_in[6];
    const float* a_src2 = (const float*)d_in[7];
    const float* a_dst2 = (const float*)d_in[8];
    const float* b2     = (const float*)d_in[9];
    const float* Wl     = (const float*)d_in[10];
    const float* bl     = (const float*)d_in[11];

    const int N = in_sizes[0] / 128;
    const int E = in_sizes[1] / 2;
    const int* src = ei;
    const int* dst = ei + E;
    const int nbuck = (N + BSIZE - 1) >> BSHIFT;
    const int CB = (E + CEPB - 1) / CEPB;   // must be <= CBPAD (E <= 2.09M)

    char* p = (char*)d_ws;
    auto alloc = [&](size_t bytes) -> void* {
        void* r = (void*)p;
        p += (bytes + 255) & ~(size_t)255;
        return r;
    };
    int*      offs        = (int*)alloc((size_t)(N + 1) * 4);
    int*      deg         = (int*)alloc((size_t)N * 4);
    int*      bucketCount = (int*)alloc(256 * 4);
    int*      blockHist   = (int*)alloc(256 * CBPAD * 4);
    int*      chunkBase   = (int*)alloc(256 * CBPAD * 4);
    unsigned* ebuf        = (unsigned*)alloc((size_t)nbuck * BCAP * 4);
    int*      csr         = (int*)alloc((size_t)E * 4);
    __bf16*   hbf         = (__bf16*)alloc((size_t)N * 64 * 2);  // gemm h out
    __bf16*   habg        = (__bf16*)alloc((size_t)N * 64 * 2);  // agg out
    float*    as_         = (float*)alloc((size_t)N * 4);
    float*    ad_         = (float*)alloc((size_t)N * 4);

    // deg and bucketCount are adjacent in the arena -> one memset covers both
    size_t degPad = ((size_t)N * 4 + 255) & ~(size_t)255;
    hipMemsetAsync(deg, 0, degPad + 256 * 4, stream);

    const int nTiles = (N + 63) / 64;
    int aggBlocks = (N * 64 + 255) / 256;

    fused_hist_gemm<<<CB + 1024, 256, 0, stream>>>(
        dst, deg, bucketCount, blockHist, E, CB,
        x, W1, a_src1, a_dst1, hbf, as_, ad_, N, nTiles);
    offs_scan<<<2 * nbuck, 512, 0, stream>>>(deg, bucketCount, blockHist,
                                             offs, chunkBase, N, E, nbuck, CB);
    edge_place<<<CB, 256, 0, stream>>>(src, dst, chunkBase, ebuf, E);
    bucket_fill<<<nbuck, 1024, 0, stream>>>(ebuf, offs, csr, N);
    gat_agg<<<aggBlocks, 256, 0, stream>>>(hbf, as_, ad_, b1, offs, csr, habg, N, 1);
    gemm_mfma2<<<1024, 256, 0, stream>>>(habg, W2, a_src2, a_dst2, hbf, as_, ad_, N, nTiles);
    gat_agg<<<aggBlocks, 256, 0, stream>>>(hbf, as_, ad_, b2, offs, csr, habg, N, 0);
    final_lsm<<<nTiles, 256, 0, stream>>>(habg, Wl, bl, (float*)d_out, N, nTiles);
}

// Round 4
// 286.669 us; speedup vs baseline: 1.4789x; 1.1799x over previous
//
#include <hip/hip_runtime.h>
#include <math.h>

// ---------------------------------------------------------------------------
// GAT x2 + linear + log_softmax on MI355X. R15.
//   - Lessons: random per-edge global atomics/writes => ~100MB write-amp
//     (R13 csr, R14 deg). Returning global atomic chains => parked blocks
//     (R11/R12). Bucketed writes => locality (R11). deg derivable in-bucket.
//   - R15 CSR build, no global returning atomics, no random 4B traffic:
//     k1 fused_hist_gemm: per-chunk LDS hist + register rank-capture ->
//        DIRECT ebuf write into fixed (bucket,chunk) slots (ECAP=112,
//        bucket-major => bucket region contiguous ~88KB). blockHist plain
//        store + fire-and-forget bucketCount (196 addrs). gemm1 co-resident.
//     k2 bucket_scan: 1 block, excl-scan bucketCount -> bucketStart.
//     k3 bucket_fill: per bucket: LDS node-hist (rank capture) -> offs =
//        bucketStart + local scan; csr writes into contiguous 32KB region.
//   - gat_agg / gemm_mfma2 / final_lsm unchanged.
// ---------------------------------------------------------------------------

#define NEG_SLOPE 0.2f
#define NEG_BIG -3.0e38f

#define BSHIFT 9
#define BSIZE 512            // nodes per bucket
#define CEPB 8192            // edges per chunk block
#define ECAP 112             // ebuf records per (bucket,chunk) slot
#define CBPAD 256            // blockHist row stride

typedef __bf16 bf16x8 __attribute__((ext_vector_type(8)));
typedef __bf16 bf16x4 __attribute__((ext_vector_type(4)));
typedef float f32x4 __attribute__((ext_vector_type(4)));

__device__ __forceinline__ float lrelu(float x) {
    return x >= 0.f ? x : NEG_SLOPE * x;
}

__device__ __forceinline__ int wave_incl_scan(int v, int lane) {
#pragma unroll
    for (int d = 1; d < 64; d <<= 1) {
        int t = __shfl_up(v, d, 64);
        if (lane >= d) v += t;
    }
    return v;
}

// ---------------- fused: hist+place || gemm1 (K=128, fp32 A hi/lo) ---------

__global__ __launch_bounds__(256) void fused_hist_gemm(
        const int* __restrict__ src, const int* __restrict__ dst,
        int* __restrict__ bucketCount, int* __restrict__ blockHist,
        unsigned* __restrict__ ebuf, int E, int CB,
        const float* __restrict__ X, const float* __restrict__ W,
        const float* __restrict__ a_src, const float* __restrict__ a_dst,
        __bf16* __restrict__ Hout, float* __restrict__ as_, float* __restrict__ ad_,
        int N, int nTiles) {
    constexpr int K = 128;
    __shared__ __bf16 Whi[64][K + 8];
    __shared__ __bf16 Wlo[64][K + 8];
    __shared__ int hist[256];

    if (blockIdx.x < (unsigned)CB) {
        // ---- hist+place path: LDS rank capture, direct slotted ebuf write --
        const int t = threadIdx.x;
        hist[t] = 0;
        __syncthreads();
        const int c = blockIdx.x;
        const int e0 = c * CEPB;
        const int e1 = min(e0 + CEPB, E);
        int rr[CEPB / 256];
#pragma unroll
        for (int i = 0; i < CEPB / 256; ++i) {
            int e = e0 + i * 256 + t;
            if (e < e1) rr[i] = atomicAdd(&hist[dst[e] >> BSHIFT], 1);
        }
        __syncthreads();
        int hv = hist[t];
        blockHist[t * CBPAD + c] = hv;                    // plain store
        if (hv > 0) atomicAdd(&bucketCount[t], hv);       // fire-and-forget
#pragma unroll
        for (int i = 0; i < CEPB / 256; ++i) {
            int e = e0 + i * 256 + t;
            if (e < e1) {
                int d = dst[e];                            // L1/L2 hot
                int b = d >> BSHIFT;
                ebuf[((size_t)b * CB + c) * ECAP + rr[i]] =
                    ((unsigned)src[e] << BSHIFT) | (unsigned)(d & (BSIZE - 1));
            }
        }
        return;
    }

    // ---- gemm path ----
    const int gbid = blockIdx.x - CB;
    for (int idx = threadIdx.x; idx < K * 64; idx += 256) {
        int k = idx >> 6, n = idx & 63;
        float w = W[idx];
        __bf16 hi = (__bf16)w;
        Whi[n][k] = hi;
        Wlo[n][k] = (__bf16)(w - (float)hi);
    }
    __syncthreads();

    const int lane  = threadIdx.x & 63;
    const int wave  = threadIdx.x >> 6;
    const int row16 = lane & 15;
    const int quad  = lane >> 4;

    float asv[4], adv[4];
#pragma unroll
    for (int t = 0; t < 4; ++t) {
        asv[t] = a_src[t * 16 + row16];
        adv[t] = a_dst[t * 16 + row16];
    }

    for (int tile = gbid; tile < nTiles; tile += 1024) {
        const int nbase = tile * 64;
        int gn = nbase + wave * 16 + row16;
        if (gn >= N) gn = N - 1;
        const float* __restrict__ xp = X + (size_t)gn * K + quad * 8;

        float4 xv[K / 16];
#pragma unroll
        for (int c = 0; c < K / 32; ++c) {
            xv[2 * c]     = *(const float4*)(xp + c * 32);
            xv[2 * c + 1] = *(const float4*)(xp + c * 32 + 4);
        }

        f32x4 acc[4] = {{0.f, 0.f, 0.f, 0.f}, {0.f, 0.f, 0.f, 0.f},
                        {0.f, 0.f, 0.f, 0.f}, {0.f, 0.f, 0.f, 0.f}};
#pragma unroll
        for (int kc = 0; kc < K; kc += 32) {
            float xs[8];
            *(float4*)&xs[0] = xv[kc / 16];
            *(float4*)&xs[4] = xv[kc / 16 + 1];
            bf16x8 ahi, alo;
#pragma unroll
            for (int j = 0; j < 8; ++j) {
                __bf16 hi = (__bf16)xs[j];
                ahi[j] = hi;
                alo[j] = (__bf16)(xs[j] - (float)hi);
            }
#pragma unroll
            for (int t = 0; t < 4; ++t) {
                bf16x8 bhi = *(const bf16x8*)&Whi[t * 16 + row16][kc + quad * 8];
                bf16x8 blo = *(const bf16x8*)&Wlo[t * 16 + row16][kc + quad * 8];
                acc[t] = __builtin_amdgcn_mfma_f32_16x16x32_bf16(ahi, bhi, acc[t], 0, 0, 0);
                acc[t] = __builtin_amdgcn_mfma_f32_16x16x32_bf16(ahi, blo, acc[t], 0, 0, 0);
                acc[t] = __builtin_amdgcn_mfma_f32_16x16x32_bf16(alo, bhi, acc[t], 0, 0, 0);
            }
        }

        float ps[4] = {0.f, 0.f, 0.f, 0.f};
        float pd[4] = {0.f, 0.f, 0.f, 0.f};
#pragma unroll
        for (int t = 0; t < 4; ++t) {
#pragma unroll
            for (int r = 0; r < 4; ++r) {
                int gm = nbase + wave * 16 + quad * 4 + r;
                if (gm < N) Hout[(size_t)gm * 64 + t * 16 + row16] = (__bf16)acc[t][r];
                ps[r] = fmaf(acc[t][r], asv[t], ps[r]);
                pd[r] = fmaf(acc[t][r], adv[t], pd[r]);
            }
        }
#pragma unroll
        for (int r = 0; r < 4; ++r) {
#pragma unroll
            for (int d = 1; d < 16; d <<= 1) {
                ps[r] += __shfl_xor(ps[r], d, 64);
                pd[r] += __shfl_xor(pd[r], d, 64);
            }
        }
        if (row16 == 0) {
#pragma unroll
            for (int r = 0; r < 4; ++r) {
                int gm = nbase + wave * 16 + quad * 4 + r;
                if (gm < N) { as_[gm] = ps[r]; ad_[gm] = pd[r]; }
            }
        }
    }
}

// ---------------- bucketStart = excl-scan(bucketCount), 1 block ------------

__global__ __launch_bounds__(256) void bucket_scan(const int* __restrict__ bucketCount,
                                                   int* __restrict__ bucketStart,
                                                   int* __restrict__ offs,
                                                   int N, int E) {
    __shared__ int wsum[4];
    const int t = threadIdx.x;
    const int lane = t & 63;
    const int w = t >> 6;
    int v = bucketCount[t];
    int incl = wave_incl_scan(v, lane);
    if (lane == 63) wsum[w] = incl;
    __syncthreads();
    int pre = 0;
#pragma unroll
    for (int i = 0; i < 4; ++i) pre += (i < w) ? wsum[i] : 0;
    bucketStart[t] = incl - v + pre;
    if (t == 0) offs[N] = E;
}

// ---------------- per-bucket: offs + csr fill (LDS ranks) ------------------

__global__ __launch_bounds__(1024) void bucket_fill(const unsigned* __restrict__ ebuf,
                                                    const int* __restrict__ blockHist,
                                                    const int* __restrict__ bucketStart,
                                                    int* __restrict__ offs,
                                                    int* __restrict__ csr,
                                                    int N, int CB) {
    __shared__ int hist[512], excls[512], bhist_s[256], wsum[16];
    const int b = blockIdx.x;
    const int t = threadIdx.x;       // 0..1023
    const int lane = t & 63;
    const int w = t >> 6;            // 0..15
    const int gbase = bucketStart[b];

    if (t < 512) hist[t] = 0;
    if (t < 256) bhist_s[t] = blockHist[b * CBPAD + t];
    __syncthreads();

    // phase 1: node-degree histogram with register rank capture.
    // wave w handles chunks c = w, w+16, ... ; <=2 rounds of 64 per chunk.
    int rr[32];
#pragma unroll
    for (int ci = 0; ci < 16; ++ci) {
        int c = w + ci * 16;
        int cnt = (c < CB) ? bhist_s[c] : 0;
        const unsigned* __restrict__ ep = ebuf + ((size_t)b * CB + c) * ECAP;
#pragma unroll
        for (int ri = 0; ri < 2; ++ri) {
            int idx = ri * 64 + lane;
            if (idx < cnt) {
                unsigned rec = ep[idx];
                rr[ci * 2 + ri] = atomicAdd(&hist[rec & (BSIZE - 1)], 1);
            }
        }
    }
    __syncthreads();

    // phase 2: 512-entry exclusive scan (waves 0..7) -> offs
    int hv = (t < 512) ? hist[t] : 0;
    int incl = wave_incl_scan(hv, lane);
    if (lane == 63 && w < 8) wsum[w] = incl;
    __syncthreads();
    if (t < 512) {
        int pre = 0;
#pragma unroll
        for (int i = 0; i < 8; ++i) pre += (i < w) ? wsum[i] : 0;
        int excl = incl - hv + pre;
        int n = b * BSIZE + t;
        if (n < N) offs[n] = gbase + excl;
        excls[t] = excl;
    }
    __syncthreads();

    // phase 3: write csr (re-read ebuf region, L2-hot)
#pragma unroll
    for (int ci = 0; ci < 16; ++ci) {
        int c = w + ci * 16;
        int cnt = (c < CB) ? bhist_s[c] : 0;
        const unsigned* __restrict__ ep = ebuf + ((size_t)b * CB + c) * ECAP;
#pragma unroll
        for (int ri = 0; ri < 2; ++ri) {
            int idx = ri * 64 + lane;
            if (idx < cnt) {
                unsigned rec = ep[idx];
                csr[gbase + excls[rec & (BSIZE - 1)] + rr[ci * 2 + ri]] =
                    (int)(rec >> BSHIFT);
            }
        }
    }
}

// ---------------- MFMA GEMM layer-2 (K=64, bf16 A, 2-term) ----------------

__global__ __launch_bounds__(256) void gemm_mfma2(const __bf16* __restrict__ X,
                                                  const float* __restrict__ W,
                                                  const float* __restrict__ a_src,
                                                  const float* __restrict__ a_dst,
                                                  __bf16* __restrict__ Hout,
                                                  float* __restrict__ as_,
                                                  float* __restrict__ ad_,
                                                  int N, int nTiles) {
    constexpr int K = 64;
    __shared__ __bf16 Whi[64][K + 8];
    __shared__ __bf16 Wlo[64][K + 8];
    for (int idx = threadIdx.x; idx < K * 64; idx += 256) {
        int k = idx >> 6, n = idx & 63;
        float w = W[idx];
        __bf16 hi = (__bf16)w;
        Whi[n][k] = hi;
        Wlo[n][k] = (__bf16)(w - (float)hi);
    }
    __syncthreads();

    const int lane  = threadIdx.x & 63;
    const int wave  = threadIdx.x >> 6;
    const int row16 = lane & 15;
    const int quad  = lane >> 4;

    float asv[4], adv[4];
#pragma unroll
    for (int t = 0; t < 4; ++t) {
        asv[t] = a_src[t * 16 + row16];
        adv[t] = a_dst[t * 16 + row16];
    }

    for (int tile = blockIdx.x; tile < nTiles; tile += gridDim.x) {
        const int nbase = tile * 64;
        int gn = nbase + wave * 16 + row16;
        if (gn >= N) gn = N - 1;
        const __bf16* __restrict__ xp = X + (size_t)gn * K + quad * 8;
        bf16x8 a0 = *(const bf16x8*)(xp);
        bf16x8 a1 = *(const bf16x8*)(xp + 32);

        f32x4 acc[4] = {{0.f, 0.f, 0.f, 0.f}, {0.f, 0.f, 0.f, 0.f},
                        {0.f, 0.f, 0.f, 0.f}, {0.f, 0.f, 0.f, 0.f}};
#pragma unroll
        for (int kc = 0; kc < K; kc += 32) {
            bf16x8 a = (kc == 0) ? a0 : a1;
#pragma unroll
            for (int t = 0; t < 4; ++t) {
                bf16x8 bhi = *(const bf16x8*)&Whi[t * 16 + row16][kc + quad * 8];
                bf16x8 blo = *(const bf16x8*)&Wlo[t * 16 + row16][kc + quad * 8];
                acc[t] = __builtin_amdgcn_mfma_f32_16x16x32_bf16(a, bhi, acc[t], 0, 0, 0);
                acc[t] = __builtin_amdgcn_mfma_f32_16x16x32_bf16(a, blo, acc[t], 0, 0, 0);
            }
        }

        float ps[4] = {0.f, 0.f, 0.f, 0.f};
        float pd[4] = {0.f, 0.f, 0.f, 0.f};
#pragma unroll
        for (int t = 0; t < 4; ++t) {
#pragma unroll
            for (int r = 0; r < 4; ++r) {
                int gm = nbase + wave * 16 + quad * 4 + r;
                if (gm < N) Hout[(size_t)gm * 64 + t * 16 + row16] = (__bf16)acc[t][r];
                ps[r] = fmaf(acc[t][r], asv[t], ps[r]);
                pd[r] = fmaf(acc[t][r], adv[t], pd[r]);
            }
        }
#pragma unroll
        for (int r = 0; r < 4; ++r) {
#pragma unroll
            for (int d = 1; d < 16; d <<= 1) {
                ps[r] += __shfl_xor(ps[r], d, 64);
                pd[r] += __shfl_xor(pd[r], d, 64);
            }
        }
        if (row16 == 0) {
#pragma unroll
            for (int r = 0; r < 4; ++r) {
                int gm = nbase + wave * 16 + quad * 4 + r;
                if (gm < N) { as_[gm] = ps[r]; ad_[gm] = pd[r]; }
            }
        }
    }
}

// ---------------- fused segment softmax + aggregation (4x16, bf16x4) -------

__global__ __launch_bounds__(256) void gat_agg(const __bf16* __restrict__ h,
                                               const float* __restrict__ as_,
                                               const float* __restrict__ ad_,
                                               const float* __restrict__ bias,
                                               const int* __restrict__ offs,
                                               const int* __restrict__ csr,
                                               __bf16* __restrict__ out,
                                               int N, int do_relu) {
    int gtid = blockIdx.x * blockDim.x + threadIdx.x;
    int n = __builtin_amdgcn_readfirstlane(gtid >> 6);
    if (n >= N) return;
    const int lane = threadIdx.x & 63;
    const int g  = lane >> 4;   // edge group 0..3
    const int fl = lane & 15;   // feature quad index

    int beg = offs[n], end = offs[n + 1];
    float adn = ad_[n];
    float p_self = __expf(lrelu(as_[n] + adn));

    float den = p_self;
    float ax, ay, az, aw;
    {
        bf16x4 t = *(const bf16x4*)(h + (size_t)n * 64 + fl * 4);
        float m0 = (g == 0) ? p_self : 0.f;
        ax = m0 * (float)t[0];
        ay = m0 * (float)t[1];
        az = m0 * (float)t[2];
        aw = m0 * (float)t[3];
    }

    for (int c0 = beg; c0 < end; c0 += 64) {
        int cnt = end - c0;
        if (cnt > 64) cnt = 64;
        int   s_l = (lane < cnt) ? csr[c0 + lane] : 0;
        float p_l = (lane < cnt) ? __expf(lrelu(as_[s_l] + adn)) : 0.f;
        float csum = p_l;
#pragma unroll
        for (int d = 32; d; d >>= 1) csum += __shfl_xor(csum, d, 64);
        den += csum;

        int rounds = (cnt + 3) >> 2;
        for (int r = 0; r < rounds; r += 4) {
            int j0 = (r + 0) * 4 + g, j1 = (r + 1) * 4 + g;
            int j2 = (r + 2) * 4 + g, j3 = (r + 3) * 4 + g;
            float w0 = __shfl(p_l, j0, 64), w1 = __shfl(p_l, j1, 64);
            float w2 = __shfl(p_l, j2, 64), w3 = __shfl(p_l, j3, 64);
            int s0 = __shfl(s_l, j0, 64), s1 = __shfl(s_l, j1, 64);
            int s2 = __shfl(s_l, j2, 64), s3 = __shfl(s_l, j3, 64);
            bf16x4 h0 = *(const bf16x4*)(h + (size_t)s0 * 64 + fl * 4);
            bf16x4 h1 = *(const bf16x4*)(h + (size_t)s1 * 64 + fl * 4);
            bf16x4 h2 = *(const bf16x4*)(h + (size_t)s2 * 64 + fl * 4);
            bf16x4 h3 = *(const bf16x4*)(h + (size_t)s3 * 64 + fl * 4);
            ax = fmaf(w0, (float)h0[0], ax); ay = fmaf(w0, (float)h0[1], ay);
            az = fmaf(w0, (float)h0[2], az); aw = fmaf(w0, (float)h0[3], aw);
            ax = fmaf(w1, (float)h1[0], ax); ay = fmaf(w1, (float)h1[1], ay);
            az = fmaf(w1, (float)h1[2], az); aw = fmaf(w1, (float)h1[3], aw);
            ax = fmaf(w2, (float)h2[0], ax); ay = fmaf(w2, (float)h2[1], ay);
            az = fmaf(w2, (float)h2[2], az); aw = fmaf(w2, (float)h2[3], aw);
            ax = fmaf(w3, (float)h3[0], ax); ay = fmaf(w3, (float)h3[1], ay);
            az = fmaf(w3, (float)h3[2], az); aw = fmaf(w3, (float)h3[3], aw);
        }
    }

#pragma unroll
    for (int d = 16; d <= 32; d <<= 1) {
        ax += __shfl_xor(ax, d, 64);
        ay += __shfl_xor(ay, d, 64);
        az += __shfl_xor(az, d, 64);
        aw += __shfl_xor(aw, d, 64);
    }
    if (g == 0) {
        float inv = 1.f / (den + 1e-16f);
        const float4 b4 = *(const float4*)(bias + fl * 4);
        bf16x4 ov;
        float o0 = fmaf(ax, inv, b4.x);
        float o1 = fmaf(ay, inv, b4.y);
        float o2 = fmaf(az, inv, b4.z);
        float o3 = fmaf(aw, inv, b4.w);
        if (do_relu) {
            o0 = fmaxf(o0, 0.f); o1 = fmaxf(o1, 0.f);
            o2 = fmaxf(o2, 0.f); o3 = fmaxf(o3, 0.f);
        }
        ov[0] = (__bf16)o0; ov[1] = (__bf16)o1;
        ov[2] = (__bf16)o2; ov[3] = (__bf16)o3;
        *(bf16x4*)(out + (size_t)n * 64 + fl * 4) = ov;
    }
}

// ---------------- final linear (bf16 A, 2-term) + log_softmax --------------

__global__ __launch_bounds__(256) void final_lsm(const __bf16* __restrict__ h,
                                                 const float* __restrict__ Wl,
                                                 const float* __restrict__ bl,
                                                 float* __restrict__ out,
                                                 int N, int nTiles) {
    __shared__ __bf16 Whi[48][72];
    __shared__ __bf16 Wlo[48][72];
    __shared__ float bls[48];
    for (int idx = threadIdx.x; idx < 48 * 64; idx += 256) {
        int c = idx >> 6, k = idx & 63;
        float w = (c < 40) ? Wl[k * 40 + c] : 0.f;
        __bf16 hi = (__bf16)w;
        Whi[c][k] = hi;
        Wlo[c][k] = (__bf16)(w - (float)hi);
    }
    if (threadIdx.x < 48) bls[threadIdx.x] = (threadIdx.x < 40) ? bl[threadIdx.x] : 0.f;
    __syncthreads();

    const int lane  = threadIdx.x & 63;
    const int wave  = threadIdx.x >> 6;
    const int col16 = lane & 15;
    const int quad  = lane >> 4;

    for (int tile = blockIdx.x; tile < nTiles; tile += gridDim.x) {
        const int nbase = tile * 64;
        int gn = nbase + wave * 16 + col16;
        if (gn >= N) gn = N - 1;
        const __bf16* __restrict__ xp = h + (size_t)gn * 64 + quad * 8;
        bf16x8 a0 = *(const bf16x8*)(xp);
        bf16x8 a1 = *(const bf16x8*)(xp + 32);

        f32x4 acc[3] = {{0.f, 0.f, 0.f, 0.f}, {0.f, 0.f, 0.f, 0.f},
                        {0.f, 0.f, 0.f, 0.f}};
#pragma unroll
        for (int kc = 0; kc < 64; kc += 32) {
            bf16x8 a = (kc == 0) ? a0 : a1;
#pragma unroll
            for (int t = 0; t < 3; ++t) {
                bf16x8 bhi = *(const bf16x8*)&Whi[t * 16 + col16][kc + quad * 8];
                bf16x8 blo = *(const bf16x8*)&Wlo[t * 16 + col16][kc + quad * 8];
                acc[t] = __builtin_amdgcn_mfma_f32_16x16x32_bf16(a, bhi, acc[t], 0, 0, 0);
                acc[t] = __builtin_amdgcn_mfma_f32_16x16x32_bf16(a, blo, acc[t], 0, 0, 0);
            }
        }

#pragma unroll
        for (int r = 0; r < 4; ++r) {
            int gm = nbase + wave * 16 + quad * 4 + r;
            float l0 = acc[0][r] + bls[col16];
            float l1 = acc[1][r] + bls[16 + col16];
            float l2 = (col16 < 8) ? (acc[2][r] + bls[32 + col16]) : NEG_BIG;
            float mx = fmaxf(fmaxf(l0, l1), l2);
#pragma unroll
            for (int d = 1; d < 16; d <<= 1) mx = fmaxf(mx, __shfl_xor(mx, d, 64));
            float s = __expf(l0 - mx) + __expf(l1 - mx) +
                      ((col16 < 8) ? __expf(l2 - mx) : 0.f);
#pragma unroll
            for (int d = 1; d < 16; d <<= 1) s += __shfl_xor(s, d, 64);
            float lse = mx + __logf(s);
            if (gm < N) {
                out[(size_t)gm * 40 + col16]      = l0 - lse;
                out[(size_t)gm * 40 + 16 + col16] = l1 - lse;
                if (col16 < 8) out[(size_t)gm * 40 + 32 + col16] = l2 - lse;
            }
        }
    }
}

// ---------------- launch ----------------

extern "C" void kernel_launch(void* const* d_in, const int* in_sizes, int n_in,
                              void* d_out, int out_size, void* d_ws, size_t ws_size,
                              hipStream_t stream) {
    const float* x      = (const float*)d_in[0];
    const int*   ei     = (const int*)d_in[1];
    const float* W1     = (const float*)d_in[2];
    const float* a_src1 = (const float*)d_in[3];
    const float* a_dst1 = (const float*)d_in[4];
    const float* b1     = (const float*)d_in[5];
    const float* W2     = (const float*)d_in[6];
    const float* a_src2 = (const float*)d_in[7];
    const float* a_dst2 = (const float*)d_in[8];
    const float* b2     = (const float*)d_in[9];
    const float* Wl     = (const float*)d_in[10];
    const float* bl     = (const float*)d_in[11];

    const int N = in_sizes[0] / 128;
    const int E = in_sizes[1] / 2;
    const int* src = ei;
    const int* dst = ei + E;
    const int nbuck = (N + BSIZE - 1) >> BSHIFT;
    const int CB = (E + CEPB - 1) / CEPB;   // must be <= 256

    char* p = (char*)d_ws;
    auto alloc = [&](size_t bytes) -> void* {
        void* r = (void*)p;
        p += (bytes + 255) & ~(size_t)255;
        return r;
    };
    int*      offs        = (int*)alloc((size_t)(N + 1) * 4);
    int*      bucketCount = (int*)alloc(256 * 4);
    int*      bucketStart = (int*)alloc(256 * 4);
    int*      blockHist   = (int*)alloc(256 * CBPAD * 4);
    unsigned* ebuf        = (unsigned*)alloc((size_t)nbuck * CB * ECAP * 4);
    int*      csr         = (int*)alloc((size_t)E * 4);
    __bf16*   hbf         = (__bf16*)alloc((size_t)N * 64 * 2);  // gemm h out
    __bf16*   habg        = (__bf16*)alloc((size_t)N * 64 * 2);  // agg out
    float*    as_         = (float*)alloc((size_t)N * 4);
    float*    ad_         = (float*)alloc((size_t)N * 4);

    hipMemsetAsync(bucketCount, 0, 256 * 4, stream);

    const int nTiles = (N + 63) / 64;
    int aggBlocks = (N * 64 + 255) / 256;

    fused_hist_gemm<<<CB + 1024, 256, 0, stream>>>(
        src, dst, bucketCount, blockHist, ebuf, E, CB,
        x, W1, a_src1, a_dst1, hbf, as_, ad_, N, nTiles);
    bucket_scan<<<1, 256, 0, stream>>>(bucketCount, bucketStart, offs, N, E);
    bucket_fill<<<nbuck, 1024, 0, stream>>>(ebuf, blockHist, bucketStart,
                                            offs, csr, N, CB);
    gat_agg<<<aggBlocks, 256, 0, stream>>>(hbf, as_, ad_, b1, offs, csr, habg, N, 1);
    gemm_mfma2<<<1024, 256, 0, stream>>>(habg, W2, a_src2, a_dst2, hbf, as_, ad_, N, nTiles);
    gat_agg<<<aggBlocks, 256, 0, stream>>>(hbf, as_, ad_, b2, offs, csr, habg, N, 0);
    final_lsm<<<nTiles, 256, 0, stream>>>(habg, Wl, bl, (float*)d_out, N, nTiles);
}